// Round 11
// baseline (2791.228 us; speedup 1.0000x reference)
//
#include <hip/hip_runtime.h>
#include <math.h>

#define Hh 240
#define Ww 480
#define HW 115200      // Hh*Ww
#define Cc 128
#define Kk 1152        // Cc*9
#define HALFW 240      // Ww/2
#define NB_RED 1440
#define WLCAP 4194304

typedef unsigned int u32;
typedef unsigned short u16;
typedef short bf16x8 __attribute__((ext_vector_type(8)));   // 8 bf16 = 4 VGPR
typedef float f32x4 __attribute__((ext_vector_type(4)));
typedef __attribute__((address_space(3))) u32 lds_u32;
typedef const __attribute__((address_space(1))) u32 glb_u32;

// ---------------------------------------------------------------------------
// bf16 split helpers: x == bf2f(x1)+bf2f(x2)+bf2f(x3) EXACTLY (3x8=24 bits)
// ---------------------------------------------------------------------------
__device__ __forceinline__ u16 f2bf(float x) {
    u32 u = __float_as_uint(x);
    u32 r = (u + 0x7fffu + ((u >> 16) & 1u)) >> 16;
    return (u16)r;
}
__device__ __forceinline__ float bf2f(u16 h) { return __uint_as_float(((u32)h) << 16); }

// geo_pad spatial index (channel-independent part)
__device__ __forceinline__ int geo_sidx(int r, int c) {
    int wv = (c < 0) ? (Ww - 1) : ((c >= Ww) ? 0 : c);
    int rr;
    if (r < 0)        { rr = 0;      wv = (wv >= HALFW) ? wv - HALFW : wv + HALFW; }
    else if (r >= Hh) { rr = Hh - 1; wv = (wv >= HALFW) ? wv - HALFW : wv + HALFW; }
    else              { rr = r; }
    return rr * Ww + wv;
}

__device__ __forceinline__ float padfetch(const float* __restrict__ p, int yi, int xj) {
    return p[geo_sidx(yi - 1, xj - 1)];
}

// small-angle double sincos (|x| <~ 0.7), libm fallback — IDENTICAL to round 2
__device__ __forceinline__ void sincos_small(double x, double* s, double* c) {
    double x2 = x * x;
    if (x2 > 0.49) { *s = sin(x); *c = cos(x); return; }
    *s = x * (1.0 + x2 * (-1.6666666666666666e-1 + x2 * (8.3333333333333333e-3 +
         x2 * (-1.9841269841269841e-4 + x2 * (2.7557319223985893e-6 - x2 * 2.5052108385441720e-8)))));
    *c = 1.0 + x2 * (-0.5 + x2 * (4.1666666666666666e-2 + x2 * (-1.3888888888888889e-3 +
         x2 * (2.4801587301587302e-5 - x2 * 2.7557319223985893e-7))));
}

// fp64 trig + fp32 bicubic tail shared by both snipers; writes out[idx].
__device__ __forceinline__ void snipe_tail(double u, double v, double dt,
                                           double phi_s, double phi_c, double lam,
                                           const float* __restrict__ plane,
                                           float* __restrict__ outp)
{
    const double TWO_PI = 6.2831853071795864769252867665590;
    const double PI_D   = 3.1415926535897932384626433832795;

    double lonp = -u * dt, latp = -v * dt;
    double slp, clp, slo, clo;
    sincos_small(latp, &slp, &clp);
    sincos_small(lonp, &slo, &clo);

    double sinlat = slp * phi_c + clp * clo * phi_s;
    sinlat = fmin(fmax(sinlat, -1.0 + 1e-7), 1.0 - 1e-7);
    double lat_dep = asin(sinlat);

    double num = clp * slo;
    double den = clp * clo * phi_c - slp * phi_s;
    double lon_dep = lam + atan2(num, den);
    double xr = lon_dep + TWO_PI;
    xr = xr - floor(xr / TWO_PI) * TWO_PI;

    double gx = (xr / TWO_PI * 2.0 - 1.0) * (480.0 / 482.0);
    double gy = (lat_dep / PI_D * 2.0 - 1.0) * (240.0 / 242.0);
    double ixd = fmin(fmax((gx + 1.0) * 0.5 * 481.0, 0.0), 481.0);
    double iyd = fmin(fmax((gy + 1.0) * 0.5 * 241.0, 0.0), 241.0);

    double x0d = floor(ixd), y0d = floor(iyd);
    float fx = (float)(ixd - x0d), fy = (float)(iyd - y0d);
    int x0 = (int)x0d, y0 = (int)y0d;

    const float a = -0.75f;
    float wx[4], wy[4];
    {
        float t = fx;
        float t1 = 1.f + t, t2 = 2.f - t, s1 = 1.f - t;
        wx[0] = ((a * t1 - 5.f * a) * t1 + 8.f * a) * t1 - 4.f * a;
        wx[1] = ((a + 2.f) * t - (a + 3.f)) * t * t + 1.f;
        wx[2] = ((a + 2.f) * s1 - (a + 3.f)) * s1 * s1 + 1.f;
        wx[3] = ((a * t2 - 5.f * a) * t2 + 8.f * a) * t2 - 4.f * a;
        t = fy;
        t1 = 1.f + t; t2 = 2.f - t; s1 = 1.f - t;
        wy[0] = ((a * t1 - 5.f * a) * t1 + 8.f * a) * t1 - 4.f * a;
        wy[1] = ((a + 2.f) * t - (a + 3.f)) * t * t + 1.f;
        wy[2] = ((a + 2.f) * s1 - (a + 3.f)) * s1 * s1 + 1.f;
        wy[3] = ((a * t2 - 5.f * a) * t2 + 8.f * a) * t2 - 4.f * a;
    }
    float accv = 0.f;
    #pragma unroll
    for (int i = 0; i < 4; i++) {
        int yi = min(max(y0 + i - 1, 0), 241);
        float row = 0.f;
        #pragma unroll
        for (int j = 0; j < 4; j++) {
            int xj = min(max(x0 + j - 1, 0), 481);
            row = fmaf(wx[j], padfetch(plane, yi, xj), row);
        }
        accv = fmaf(wy[i], row, accv);
    }
    *outp = accv;
}

// ---------------------------------------------------------------------------
// reorder+split weights [N][Kk] fp32 -> per-K-step fragment-major bf16 units:
// out[ktblk][U][j]: U = p*(NN/16)*64 + ntile*64 + part*16 + nlow,
//   value = plane_p( w[ntile*16+nlow][ktblk*32 + part*8 + j] ).
// Exactly the LDS image conv_mfma wants -> linear DMA staging.
// ---------------------------------------------------------------------------
__global__ void reorder_w(const float* __restrict__ w, u16* __restrict__ outp, int NN) {
    int idx = blockIdx.x * 256 + threadIdx.x;
    int total = 3 * NN * Kk;
    if (idx >= total) return;
    int per_kt = 3 * NN * 32;
    int t = idx / per_kt;
    int rem = idx - t * per_kt;
    int U = rem >> 3, j = rem & 7;
    int NT64 = (NN / 16) * 64;
    int p = U / NT64;
    int r2 = U - p * NT64;
    int ntile = r2 >> 6, part = (r2 >> 4) & 3, nlow = r2 & 15;
    int n = ntile * 16 + nlow;
    int k = t * 32 + part * 8 + j;
    float x = w[(size_t)n * Kk + k];
    u16 a = f2bf(x); float r1 = x - bf2f(a);
    u16 b = f2bf(r1); float rr = r1 - bf2f(b);
    outp[idx] = (p == 0) ? a : ((p == 1) ? b : f2bf(rr));
}

// ---------------------------------------------------------------------------
// MFMA implicit-GEMM conv (bf16x3, 6-pass). Tile 128(M) x NN(N), K-step 32.
// 512 threads, 8 waves (2M x 4N), DOUBLE-BUFFERED LDS, 1 barrier per K-step.
// B staged via linear global_load_lds DMA (issued at phase start, lands during
// MFMA); A loads issued early, split+write after MFMA (T14 split).
// Per-acc (pb,pa) FMA order identical to rounds 7-10 -> bit-exact.
// ---------------------------------------------------------------------------
template<int NN>
__global__ __launch_bounds__(512)
void conv_mfma(const float* __restrict__ in,     // [Cc][HW] batch plane
               const u16*  __restrict__ wspr,    // reordered planes
               const float* __restrict__ bias,   // [NN]
               float* __restrict__ out)          // [NN][HW]
{
    constexpr int NT     = NN / 64;              // n-frags per wave (4 N-waves)
    constexpr int NTILES = NN / 16;
    __shared__ short Al[2][3][8][4][16][8];      // [buf][p][mtile][kg][lr][8]
    __shared__ short Bl[2][3][NTILES][4][16][8]; // [buf][p][ntile][kg][lr][8]

    const int tid  = threadIdx.x;
    const int lane = tid & 63;
    const int wave = tid >> 6;                   // 0..7
    const int wm = wave & 1, wn = wave >> 1;     // 2M x 4N
    const int lr = lane & 15, kg = lane >> 4;
    const int m0 = blockIdx.x * 128;

    // A staging identity: thread stages m = tid&127, k-group grp = tid>>7 (8 k)
    const int ms   = tid & 127;
    const int grp  = tid >> 7;                   // 0..3
    const int mt_s = ms >> 4, lr_s = ms & 15;
    const int gm = m0 + ms;
    const int h = gm / Ww, w = gm - h * Ww;
    int sidx[9];
    #pragma unroll
    for (int q = 0; q < 9; q++) sidx[q] = geo_sidx(h + q / 3 - 1, w + q % 3 - 1);

    constexpr int NCH = (3 * NN * 32 / 8) / 512; // 16B units per thread per kt

    f32x4 acc[4][NT] = {};

    auto stageB = [&](int buf, int kt) {
        const u16* src = wspr + (size_t)(kt >> 5) * (3 * NN * 32) + (size_t)tid * 8;
        short* dst = &Bl[buf][0][0][0][0][0];
        #pragma unroll
        for (int cg = 0; cg < NCH; cg++) {
            __builtin_amdgcn_global_load_lds(
                (glb_u32*)(src + (size_t)cg * 4096),
                (lds_u32*)(dst + (size_t)(cg * 512 + tid) * 8), 16, 0, 0);
        }
    };
    auto loadA = [&](int kt, float* xv) {
        int k = kt + grp * 8;
        int ic = k / 9, t9 = k - ic * 9;
        #pragma unroll
        for (int j = 0; j < 8; j++) {
            xv[j] = in[ic * HW + sidx[t9]];
            if (++t9 == 9) { t9 = 0; ic++; }
        }
    };
    auto writeA = [&](int buf, const float* xv) {
        bf16x8 v0, v1, v2;
        #pragma unroll
        for (int j = 0; j < 8; j++) {
            float x = xv[j];
            u16 a = f2bf(x); float r1 = x - bf2f(a);
            u16 b = f2bf(r1); float r2 = r1 - bf2f(b);
            v0[j] = (short)a; v1[j] = (short)b; v2[j] = (short)f2bf(r2);
        }
        *(bf16x8*)&Al[buf][0][mt_s][grp][lr_s][0] = v0;
        *(bf16x8*)&Al[buf][1][mt_s][grp][lr_s][0] = v1;
        *(bf16x8*)&Al[buf][2][mt_s][grp][lr_s][0] = v2;
    };

    // prologue: stage tile 0 into buf 0
    {
        float xv[8];
        stageB(0, 0);
        loadA(0, xv);
        writeA(0, xv);
    }

    int cur = 0;
    for (int kt = 0; kt < Kk; kt += 32) {
        __syncthreads();                         // cur staged (DMA drained)
        // hoist A fragments (12 lane-order ds_reads, conflict-free)
        bf16x8 af[3][4];
        #pragma unroll
        for (int pa = 0; pa < 3; pa++)
            #pragma unroll
            for (int mt = 0; mt < 4; mt++)
                af[pa][mt] = *(const bf16x8*)&Al[cur][pa][wm * 4 + mt][kg][lr][0];

        float xv[8];
        const bool more = (kt + 32 < Kk);
        if (more) {
            stageB(cur ^ 1, kt + 32);            // DMA lands during MFMA
            loadA(kt + 32, xv);                  // loads land during MFMA
        }

        // 6 passes: per-acc (pb,pa) order == rounds 7-10 (bit-exact)
        #pragma unroll
        for (int pb = 0; pb < 3; pb++) {
            #pragma unroll
            for (int nt = 0; nt < NT; nt++) {
                bf16x8 bq = *(const bf16x8*)&Bl[cur][pb][wn * NT + nt][kg][lr][0];
                #pragma unroll
                for (int pa = 0; pa < 3 - pb; pa++)
                    #pragma unroll
                    for (int mt = 0; mt < 4; mt++)
                        acc[mt][nt] = __builtin_amdgcn_mfma_f32_16x16x32_bf16(
                            af[pa][mt], bq, acc[mt][nt], 0, 0, 0);
            }
        }
        if (more) writeA(cur ^ 1, xv);           // split+write after MFMA
        cur ^= 1;
    }

    #pragma unroll
    for (int mt = 0; mt < 4; mt++) {
        int mbase = m0 + wm * 64 + mt * 16 + kg * 4;
        #pragma unroll
        for (int nt = 0; nt < NT; nt++) {
            int n = wn * (NN / 4) + nt * 16 + lr;
            float bv = bias[n];
            float4 o;
            o.x = acc[mt][nt][0] + bv;
            o.y = acc[mt][nt][1] + bv;
            o.z = acc[mt][nt][2] + bv;
            o.w = acc[mt][nt][3] + bv;
            *(float4*)&out[(size_t)n * HW + mbase] = o;
        }
    }
}

// ---------------------------------------------------------------------------
// deterministic two-stage LayerNorm stats (unchanged)
// ---------------------------------------------------------------------------
__global__ __launch_bounds__(256)
void reduce_stats(const float* __restrict__ y, float* __restrict__ part) {
    const int n4 = (Cc * HW) / 4;
    float s = 0.f, ss = 0.f;
    for (int i = blockIdx.x * 256 + threadIdx.x; i < n4; i += NB_RED * 256) {
        float4 v = ((const float4*)y)[i];
        s  += v.x + v.y + v.z + v.w;
        ss += v.x * v.x + v.y * v.y + v.z * v.z + v.w * v.w;
    }
    #pragma unroll
    for (int o = 32; o > 0; o >>= 1) { s += __shfl_down(s, o); ss += __shfl_down(ss, o); }
    __shared__ float ls[4], lss[4];
    int wid = threadIdx.x >> 6, lane = threadIdx.x & 63;
    if (lane == 0) { ls[wid] = s; lss[wid] = ss; }
    __syncthreads();
    if (threadIdx.x == 0) {
        part[blockIdx.x * 2]     = ls[0] + ls[1] + ls[2] + ls[3];
        part[blockIdx.x * 2 + 1] = lss[0] + lss[1] + lss[2] + lss[3];
    }
}

__global__ __launch_bounds__(256)
void finalize_stats(const float* __restrict__ part, float* __restrict__ stats) {
    float s = 0.f, ss = 0.f;
    for (int i = threadIdx.x; i < NB_RED; i += 256) { s += part[2 * i]; ss += part[2 * i + 1]; }
    #pragma unroll
    for (int o = 32; o > 0; o >>= 1) { s += __shfl_down(s, o); ss += __shfl_down(ss, o); }
    __shared__ float ls[4], lss[4];
    int wid = threadIdx.x >> 6, lane = threadIdx.x & 63;
    if (lane == 0) { ls[wid] = s; lss[wid] = ss; }
    __syncthreads();
    if (threadIdx.x == 0) {
        stats[0] = ls[0] + ls[1] + ls[2] + ls[3];
        stats[1] = lss[0] + lss[1] + lss[2] + lss[3];
    }
}

__global__ void norm_silu(float* __restrict__ y, const float* __restrict__ g,
                          const float* __restrict__ bb, const float* __restrict__ stats) {
    int i = blockIdx.x * 256 + threadIdx.x;
    if (i >= Cc * HW) return;
    const float invN = 1.f / (float)(Cc * HW);
    float mu  = stats[0] * invN;
    float var = stats[1] * invN - mu * mu;
    float inv = rsqrtf(var + 1e-5f);
    float z = (y[i] - mu) * inv * g[i] + bb[i];
    y[i] = z / (1.f + expf(-z));
}

// ---------------------------------------------------------------------------
// semilag fast path (pure fp32). Pole rows handled by sniper_rows.
// ---------------------------------------------------------------------------
__global__ __launch_bounds__(256)
void semilag(const float* __restrict__ vel, const float* __restrict__ hid,
             const float* __restrict__ latg, const float* __restrict__ lng,
             const float* __restrict__ dtp, float* __restrict__ out,
             u32* __restrict__ wl, u32* __restrict__ wlcnt)
{
    int idx = blockIdx.x * 256 + threadIdx.x;
    if (idx >= Cc * HW) return;
    int c = idx / HW;
    int m = idx - c * HW;

    const float PI2F = 6.28318530717958647692f;

    float uf = vel[idx];
    float vf = vel[Cc * HW + idx];
    float dtf = dtp[0];
    float phi = latg[m], lam = lng[m];
    float sphi = sinf(phi), cphi = cosf(phi);

    float lonp = -uf * dtf, latp = -vf * dtf;
    float slp = sinf(latp), clp = cosf(latp);
    float slo = sinf(lonp), clo = cosf(lonp);
    float sinlat = slp * cphi + clp * clo * sphi;
    float num = clp * slo;
    float den = clp * clo * cphi - slp * sphi;
    float r2 = num * num + den * den;

    float lon_w = lam + atan2f(num, den) + PI2F;
    lon_w = lon_w - floorf(lon_w / PI2F) * PI2F;
    float seam = fminf(lon_w, PI2F - lon_w);

    bool pole = (m < 2 * Ww) | (m >= HW - 2 * Ww);
    bool snipe = !pole & ((r2 < 1e-4f) | (fabsf(sinlat) > 1.f - 1e-5f) | (seam < 1e-3f));
    if (snipe) {
        u32 s = atomicAdd(wlcnt, 1u);
        if (s < WLCAP) wl[s] = (u32)idx;
    }

    float sl = fminf(fmaxf(sinlat, -1.f + 1e-7f), 1.f - 1e-7f);
    float lat_dep = asinf(sl);
    float gx = (lon_w / PI2F * 2.f - 1.f) * (480.f / 482.f);
    float gy = (lat_dep / 3.14159265358979323846f * 2.f - 1.f) * (240.f / 242.f);
    double ixd = (double)fminf(fmaxf((gx + 1.f) * 0.5f * 481.f, 0.f), 481.f);
    double iyd = (double)fminf(fmaxf((gy + 1.f) * 0.5f * 241.f, 0.f), 241.f);

    double x0d = floor(ixd), y0d = floor(iyd);
    float fx = (float)(ixd - x0d), fy = (float)(iyd - y0d);
    int x0 = (int)x0d, y0 = (int)y0d;

    const float a = -0.75f;
    float wx[4], wy[4];
    {
        float t = fx;
        float t1 = 1.f + t, t2 = 2.f - t, s1 = 1.f - t;
        wx[0] = ((a * t1 - 5.f * a) * t1 + 8.f * a) * t1 - 4.f * a;
        wx[1] = ((a + 2.f) * t - (a + 3.f)) * t * t + 1.f;
        wx[2] = ((a + 2.f) * s1 - (a + 3.f)) * s1 * s1 + 1.f;
        wx[3] = ((a * t2 - 5.f * a) * t2 + 8.f * a) * t2 - 4.f * a;
        t = fy;
        t1 = 1.f + t; t2 = 2.f - t; s1 = 1.f - t;
        wy[0] = ((a * t1 - 5.f * a) * t1 + 8.f * a) * t1 - 4.f * a;
        wy[1] = ((a + 2.f) * t - (a + 3.f)) * t * t + 1.f;
        wy[2] = ((a + 2.f) * s1 - (a + 3.f)) * s1 * s1 + 1.f;
        wy[3] = ((a * t2 - 5.f * a) * t2 + 8.f * a) * t2 - 4.f * a;
    }

    const float* plane = hid + (size_t)c * HW;
    float accv = 0.f;
    #pragma unroll
    for (int i = 0; i < 4; i++) {
        int yi = min(max(y0 + i - 1, 0), 241);
        float row = 0.f;
        #pragma unroll
        for (int j = 0; j < 4; j++) {
            int xj = min(max(x0 + j - 1, 0), 481);
            row = fmaf(wx[j], padfetch(plane, yi, xj), row);
        }
        accv = fmaf(wy[i], row, accv);
    }
    out[idx] = accv;
}

// ---------------------------------------------------------------------------
// sniper_rows: pole rows {0,1,238,239} — one block per spatial pixel.
// ---------------------------------------------------------------------------
__global__ __launch_bounds__(256)
void sniper_rows(const float* __restrict__ y1, const float* __restrict__ w2,
                 const float* __restrict__ b2, const float* __restrict__ hid,
                 const float* __restrict__ latg, const float* __restrict__ lng,
                 const float* __restrict__ dtp, float* __restrict__ out)
{
    __shared__ float xl[Kk];
    __shared__ double resd[256];

    const int tid = threadIdx.x;
    const int ri  = blockIdx.x / Ww;
    const int col = blockIdx.x - ri * Ww;
    const int r   = (ri < 2) ? ri : (236 + ri);   // 0,1,238,239
    const int m   = r * Ww + col;

    for (int k = tid; k < Kk; k += 256) {
        int ic = k / 9, t9 = k - ic * 9;
        xl[k] = y1[ic * HW + geo_sidx(r + t9 / 3 - 1, col + t9 % 3 - 1)];
    }
    __syncthreads();

    {
        const float* wrow = w2 + (size_t)tid * Kk;
        double a0 = 0.0, a1 = 0.0, a2 = 0.0, a3 = 0.0;
        #pragma unroll 4
        for (int k = 0; k < Kk; k += 4) {
            a0 = fma((double)wrow[k],     (double)xl[k],     a0);
            a1 = fma((double)wrow[k + 1], (double)xl[k + 1], a1);
            a2 = fma((double)wrow[k + 2], (double)xl[k + 2], a2);
            a3 = fma((double)wrow[k + 3], (double)xl[k + 3], a3);
        }
        resd[tid] = (a0 + a1) + (a2 + a3);
    }
    __syncthreads();

    if (tid < Cc) {
        double u = (double)b2[tid] + resd[tid];
        double v = (double)b2[Cc + tid] + resd[Cc + tid];
        double dt = (double)dtp[0];
        double phi = (double)latg[m];
        snipe_tail(u, v, dt, sin(phi), cos(phi), (double)lng[m],
                   hid + (size_t)tid * HW, &out[(size_t)tid * HW + m]);
    }
}

// ---------------------------------------------------------------------------
// sniper: per worklist entry (non-pole stragglers), one wave per entry.
// ---------------------------------------------------------------------------
__global__ __launch_bounds__(256)
void sniper(const u32* __restrict__ wl, const u32* __restrict__ wlcnt,
            const float* __restrict__ y1, const float* __restrict__ w2,
            const float* __restrict__ b2, const float* __restrict__ hid,
            const float* __restrict__ latg, const float* __restrict__ lng,
            const float* __restrict__ dtp, float* __restrict__ out)
{
    const int lane = threadIdx.x & 63;
    const int wavid = (blockIdx.x * 256 + threadIdx.x) >> 6;
    const int nwaves = gridDim.x * 4;
    int n = (int)*wlcnt; if (n > WLCAP) n = WLCAP;

    for (int e = wavid; e < n; e += nwaves) {
        u32 idx = wl[e];
        int c = idx / HW, m = idx - c * HW;
        int h = m / Ww, w = m - h * Ww;

        double su = 0.0, sv = 0.0;
        const float* wu = w2 + (size_t)c * Kk;
        const float* wv = w2 + (size_t)(Cc + c) * Kk;
        #pragma unroll
        for (int t9 = 0; t9 < 9; t9++) {
            int s = geo_sidx(h + t9 / 3 - 1, w + t9 % 3 - 1);
            #pragma unroll
            for (int q = 0; q < 2; q++) {
                int ic = q * 64 + lane;
                int k = ic * 9 + t9;
                double yv = (double)y1[ic * HW + s];
                su = fma((double)wu[k], yv, su);
                sv = fma((double)wv[k], yv, sv);
            }
        }
        #pragma unroll
        for (int o = 32; o > 0; o >>= 1) {
            su += __shfl_down(su, o);
            sv += __shfl_down(sv, o);
        }
        if (lane == 0) {
            double u = (double)b2[c] + su;
            double v = (double)b2[Cc + c] + sv;
            double dt = (double)dtp[0];
            double phi = (double)latg[m];
            snipe_tail(u, v, dt, sin(phi), cos(phi), (double)lng[m],
                       hid + (size_t)c * HW, &out[idx]);
        }
    }
}

// ---------------------------------------------------------------------------
extern "C" void kernel_launch(void* const* d_in, const int* in_sizes, int n_in,
                              void* d_out, int out_size, void* d_ws, size_t ws_size,
                              hipStream_t stream)
{
    const float* hidden = (const float*)d_in[0];
    const float* latg   = (const float*)d_in[1];
    const float* lng    = (const float*)d_in[2];
    const float* w1     = (const float*)d_in[3];
    const float* b1     = (const float*)d_in[4];
    const float* g      = (const float*)d_in[5];
    const float* lb     = (const float*)d_in[6];
    const float* w2     = (const float*)d_in[7];
    const float* b2     = (const float*)d_in[8];
    const float* dt     = (const float*)d_in[9];
    float* out = (float*)d_out;

    float* ws    = (float*)d_ws;
    float* stats = ws;
    float* part  = ws + 4;
    u32*   wlcnt = (u32*)(ws + 4 + 2 * NB_RED);
    u16*   wsp1  = (u16*)(ws + 4 + 2 * NB_RED + 4);
    u16*   wsp2  = wsp1 + (size_t)3 * Cc * Kk;
    float* y1    = (float*)(wsp2 + (size_t)3 * 2 * Cc * Kk);
    float* vel   = y1 + (size_t)Cc * HW;
    u32*   wl    = (u32*)(vel + (size_t)2 * Cc * HW);

    reorder_w<<<(3 * Cc * Kk + 255) / 256, 256, 0, stream>>>(w1, wsp1, Cc);
    reorder_w<<<(3 * 2 * Cc * Kk + 255) / 256, 256, 0, stream>>>(w2, wsp2, 2 * Cc);

    for (int b = 0; b < 2; b++) {
        const float* hb = hidden + (size_t)b * Cc * HW;
        const float* lab = latg + (size_t)b * HW;
        const float* lob = lng + (size_t)b * HW;
        float* ob = out + (size_t)b * Cc * HW;

        conv_mfma<128><<<HW / 128, 512, 0, stream>>>(hb, wsp1, b1, y1);
        reduce_stats<<<NB_RED, 256, 0, stream>>>(y1, part);
        finalize_stats<<<1, 256, 0, stream>>>(part, stats + 2 * b);
        norm_silu<<<(Cc * HW) / 256, 256, 0, stream>>>(y1, g, lb, stats + 2 * b);
        conv_mfma<256><<<HW / 128, 512, 0, stream>>>(y1, wsp2, b2, vel);
        hipMemsetAsync(wlcnt, 0, 4, stream);
        semilag<<<(Cc * HW) / 256, 256, 0, stream>>>(vel, hb, lab, lob, dt, ob, wl, wlcnt);
        sniper_rows<<<4 * Ww, 256, 0, stream>>>(y1, w2, b2, hb, lab, lob, dt, ob);
        sniper<<<2048, 256, 0, stream>>>(wl, wlcnt, y1, w2, b2, hb, lab, lob, dt, ob);
    }
}

// Round 12
// 2693.897 us; speedup vs baseline: 1.0361x; 1.0361x over previous
//
#include <hip/hip_runtime.h>
#include <math.h>

#define Hh 240
#define Ww 480
#define HW 115200      // Hh*Ww
#define Cc 128
#define Kk 1152        // Cc*9
#define HALFW 240      // Ww/2
#define NB_RED 1440
#define WLCAP 4194304

typedef unsigned int u32;
typedef unsigned short u16;
typedef short bf16x8 __attribute__((ext_vector_type(8)));   // 8 bf16 = 4 VGPR
typedef float f32x4 __attribute__((ext_vector_type(4)));
typedef __attribute__((address_space(3))) u32 lds_u32;
typedef const __attribute__((address_space(1))) u32 glb_u32;

// ---------------------------------------------------------------------------
// bf16 split helpers: x == bf2f(x1)+bf2f(x2)+bf2f(x3) EXACTLY (3x8=24 bits)
// ---------------------------------------------------------------------------
__device__ __forceinline__ u16 f2bf(float x) {
    u32 u = __float_as_uint(x);
    u32 r = (u + 0x7fffu + ((u >> 16) & 1u)) >> 16;
    return (u16)r;
}
__device__ __forceinline__ float bf2f(u16 h) { return __uint_as_float(((u32)h) << 16); }

// geo_pad spatial index (channel-independent part)
__device__ __forceinline__ int geo_sidx(int r, int c) {
    int wv = (c < 0) ? (Ww - 1) : ((c >= Ww) ? 0 : c);
    int rr;
    if (r < 0)        { rr = 0;      wv = (wv >= HALFW) ? wv - HALFW : wv + HALFW; }
    else if (r >= Hh) { rr = Hh - 1; wv = (wv >= HALFW) ? wv - HALFW : wv + HALFW; }
    else              { rr = r; }
    return rr * Ww + wv;
}

__device__ __forceinline__ float padfetch(const float* __restrict__ p, int yi, int xj) {
    return p[geo_sidx(yi - 1, xj - 1)];
}

// small-angle double sincos (|x| <~ 0.7), libm fallback — IDENTICAL to round 2
__device__ __forceinline__ void sincos_small(double x, double* s, double* c) {
    double x2 = x * x;
    if (x2 > 0.49) { *s = sin(x); *c = cos(x); return; }
    *s = x * (1.0 + x2 * (-1.6666666666666666e-1 + x2 * (8.3333333333333333e-3 +
         x2 * (-1.9841269841269841e-4 + x2 * (2.7557319223985893e-6 - x2 * 2.5052108385441720e-8)))));
    *c = 1.0 + x2 * (-0.5 + x2 * (4.1666666666666666e-2 + x2 * (-1.3888888888888889e-3 +
         x2 * (2.4801587301587302e-5 - x2 * 2.7557319223985893e-7))));
}

// fp64 trig + fp32 bicubic tail shared by both snipers; writes out[idx].
__device__ __forceinline__ void snipe_tail(double u, double v, double dt,
                                           double phi_s, double phi_c, double lam,
                                           const float* __restrict__ plane,
                                           float* __restrict__ outp)
{
    const double TWO_PI = 6.2831853071795864769252867665590;
    const double PI_D   = 3.1415926535897932384626433832795;

    double lonp = -u * dt, latp = -v * dt;
    double slp, clp, slo, clo;
    sincos_small(latp, &slp, &clp);
    sincos_small(lonp, &slo, &clo);

    double sinlat = slp * phi_c + clp * clo * phi_s;
    sinlat = fmin(fmax(sinlat, -1.0 + 1e-7), 1.0 - 1e-7);
    double lat_dep = asin(sinlat);

    double num = clp * slo;
    double den = clp * clo * phi_c - slp * phi_s;
    double lon_dep = lam + atan2(num, den);
    double xr = lon_dep + TWO_PI;
    xr = xr - floor(xr / TWO_PI) * TWO_PI;

    double gx = (xr / TWO_PI * 2.0 - 1.0) * (480.0 / 482.0);
    double gy = (lat_dep / PI_D * 2.0 - 1.0) * (240.0 / 242.0);
    double ixd = fmin(fmax((gx + 1.0) * 0.5 * 481.0, 0.0), 481.0);
    double iyd = fmin(fmax((gy + 1.0) * 0.5 * 241.0, 0.0), 241.0);

    double x0d = floor(ixd), y0d = floor(iyd);
    float fx = (float)(ixd - x0d), fy = (float)(iyd - y0d);
    int x0 = (int)x0d, y0 = (int)y0d;

    const float a = -0.75f;
    float wx[4], wy[4];
    {
        float t = fx;
        float t1 = 1.f + t, t2 = 2.f - t, s1 = 1.f - t;
        wx[0] = ((a * t1 - 5.f * a) * t1 + 8.f * a) * t1 - 4.f * a;
        wx[1] = ((a + 2.f) * t - (a + 3.f)) * t * t + 1.f;
        wx[2] = ((a + 2.f) * s1 - (a + 3.f)) * s1 * s1 + 1.f;
        wx[3] = ((a * t2 - 5.f * a) * t2 + 8.f * a) * t2 - 4.f * a;
        t = fy;
        t1 = 1.f + t; t2 = 2.f - t; s1 = 1.f - t;
        wy[0] = ((a * t1 - 5.f * a) * t1 + 8.f * a) * t1 - 4.f * a;
        wy[1] = ((a + 2.f) * t - (a + 3.f)) * t * t + 1.f;
        wy[2] = ((a + 2.f) * s1 - (a + 3.f)) * s1 * s1 + 1.f;
        wy[3] = ((a * t2 - 5.f * a) * t2 + 8.f * a) * t2 - 4.f * a;
    }
    float accv = 0.f;
    #pragma unroll
    for (int i = 0; i < 4; i++) {
        int yi = min(max(y0 + i - 1, 0), 241);
        float row = 0.f;
        #pragma unroll
        for (int j = 0; j < 4; j++) {
            int xj = min(max(x0 + j - 1, 0), 481);
            row = fmaf(wx[j], padfetch(plane, yi, xj), row);
        }
        accv = fmaf(wy[i], row, accv);
    }
    *outp = accv;
}

// ---------------------------------------------------------------------------
// reorder+split weights [N][Kk] fp32 -> per-K-step fragment-major bf16 units
// (exactly the LDS image conv_mfma wants -> linear DMA staging).
// ---------------------------------------------------------------------------
__global__ void reorder_w(const float* __restrict__ w, u16* __restrict__ outp, int NN) {
    int idx = blockIdx.x * 256 + threadIdx.x;
    int total = 3 * NN * Kk;
    if (idx >= total) return;
    int per_kt = 3 * NN * 32;
    int t = idx / per_kt;
    int rem = idx - t * per_kt;
    int U = rem >> 3, j = rem & 7;
    int NT64 = (NN / 16) * 64;
    int p = U / NT64;
    int r2 = U - p * NT64;
    int ntile = r2 >> 6, part = (r2 >> 4) & 3, nlow = r2 & 15;
    int n = ntile * 16 + nlow;
    int k = t * 32 + part * 8 + j;
    float x = w[(size_t)n * Kk + k];
    u16 a = f2bf(x); float r1 = x - bf2f(a);
    u16 b = f2bf(r1); float rr = r1 - bf2f(b);
    outp[idx] = (p == 0) ? a : ((p == 1) ? b : f2bf(rr));
}

// ---------------------------------------------------------------------------
// MFMA implicit-GEMM conv (bf16x3, 6-pass). Tile 128(M) x NN(N), K-step 32.
// 512 threads, 8 waves (2M x 4N), SINGLE-buffered LDS (2-phase loop) so two
// blocks fit per CU; cross-block desync provides the staging/MFMA overlap.
// Per-acc (pb,pa) FMA order identical to rounds 7-11 -> bit-exact.
// ---------------------------------------------------------------------------
template<int NN>
__global__ __launch_bounds__(512)
void conv_mfma(const float* __restrict__ in,     // [Cc][HW] batch plane
               const u16*  __restrict__ wspr,    // reordered planes
               const float* __restrict__ bias,   // [NN]
               float* __restrict__ out)          // [NN][HW]
{
    constexpr int NT     = NN / 64;              // n-frags per wave (4 N-waves)
    constexpr int NTILES = NN / 16;
    __shared__ short Al[3][8][4][16][8];         // [p][mtile][kg][lr][8]
    __shared__ short Bl[3][NTILES][4][16][8];    // [p][ntile][kg][lr][8]

    const int tid  = threadIdx.x;
    const int lane = tid & 63;
    const int wave = tid >> 6;                   // 0..7
    const int wm = wave & 1, wn = wave >> 1;     // 2M x 4N
    const int lr = lane & 15, kg = lane >> 4;
    const int m0 = blockIdx.x * 128;

    // A staging identity: thread stages m = tid&127, k-group grp = tid>>7 (8 k)
    const int ms   = tid & 127;
    const int grp  = tid >> 7;                   // 0..3
    const int mt_s = ms >> 4, lr_s = ms & 15;
    const int gm = m0 + ms;
    const int h = gm / Ww, w = gm - h * Ww;
    int sidx[9];
    #pragma unroll
    for (int q = 0; q < 9; q++) sidx[q] = geo_sidx(h + q / 3 - 1, w + q % 3 - 1);

    constexpr int NCH = (3 * NN * 32 / 8) / 512; // 16B units per thread per kt

    f32x4 acc[4][NT] = {};

    for (int kt = 0; kt < Kk; kt += 32) {
        __syncthreads();                         // previous MFMA phase done
        // ---- stage B: linear DMA of the pre-reordered LDS image ----
        {
            const u16* src = wspr + (size_t)(kt >> 5) * (3 * NN * 32) + (size_t)tid * 8;
            short* dst = &Bl[0][0][0][0][0];
            #pragma unroll
            for (int cg = 0; cg < NCH; cg++) {
                __builtin_amdgcn_global_load_lds(
                    (glb_u32*)(src + (size_t)cg * 4096),
                    (lds_u32*)(dst + (size_t)(cg * 512 + tid) * 8), 16, 0, 0);
            }
        }
        // ---- stage A: fp32 gather -> bf16x3 split -> fragment-major LDS ----
        {
            int k = kt + grp * 8;
            int ic = k / 9, t9 = k - ic * 9;
            float xv[8];
            #pragma unroll
            for (int j = 0; j < 8; j++) {
                xv[j] = in[ic * HW + sidx[t9]];
                if (++t9 == 9) { t9 = 0; ic++; }
            }
            bf16x8 v0, v1, v2;
            #pragma unroll
            for (int j = 0; j < 8; j++) {
                float x = xv[j];
                u16 a = f2bf(x); float r1 = x - bf2f(a);
                u16 b = f2bf(r1); float r2 = r1 - bf2f(b);
                v0[j] = (short)a; v1[j] = (short)b; v2[j] = (short)f2bf(r2);
            }
            *(bf16x8*)&Al[0][mt_s][grp][lr_s][0] = v0;
            *(bf16x8*)&Al[1][mt_s][grp][lr_s][0] = v1;
            *(bf16x8*)&Al[2][mt_s][grp][lr_s][0] = v2;
        }
        __syncthreads();                         // staging (incl. DMA) complete

        // ---- hoist A fragments (12 lane-order ds_reads, conflict-free) ----
        bf16x8 af[3][4];
        #pragma unroll
        for (int pa = 0; pa < 3; pa++)
            #pragma unroll
            for (int mt = 0; mt < 4; mt++)
                af[pa][mt] = *(const bf16x8*)&Al[pa][wm * 4 + mt][kg][lr][0];

        // ---- 6 passes: per-acc (pb,pa) order == rounds 7-11 (bit-exact) ----
        #pragma unroll
        for (int pb = 0; pb < 3; pb++) {
            #pragma unroll
            for (int nt = 0; nt < NT; nt++) {
                bf16x8 bq = *(const bf16x8*)&Bl[pb][wn * NT + nt][kg][lr][0];
                #pragma unroll
                for (int pa = 0; pa < 3 - pb; pa++)
                    #pragma unroll
                    for (int mt = 0; mt < 4; mt++)
                        acc[mt][nt] = __builtin_amdgcn_mfma_f32_16x16x32_bf16(
                            af[pa][mt], bq, acc[mt][nt], 0, 0, 0);
            }
        }
    }

    #pragma unroll
    for (int mt = 0; mt < 4; mt++) {
        int mbase = m0 + wm * 64 + mt * 16 + kg * 4;
        #pragma unroll
        for (int nt = 0; nt < NT; nt++) {
            int n = wn * (NN / 4) + nt * 16 + lr;
            float bv = bias[n];
            float4 o;
            o.x = acc[mt][nt][0] + bv;
            o.y = acc[mt][nt][1] + bv;
            o.z = acc[mt][nt][2] + bv;
            o.w = acc[mt][nt][3] + bv;
            *(float4*)&out[(size_t)n * HW + mbase] = o;
        }
    }
}

// ---------------------------------------------------------------------------
// deterministic two-stage LayerNorm stats (unchanged)
// ---------------------------------------------------------------------------
__global__ __launch_bounds__(256)
void reduce_stats(const float* __restrict__ y, float* __restrict__ part) {
    const int n4 = (Cc * HW) / 4;
    float s = 0.f, ss = 0.f;
    for (int i = blockIdx.x * 256 + threadIdx.x; i < n4; i += NB_RED * 256) {
        float4 v = ((const float4*)y)[i];
        s  += v.x + v.y + v.z + v.w;
        ss += v.x * v.x + v.y * v.y + v.z * v.z + v.w * v.w;
    }
    #pragma unroll
    for (int o = 32; o > 0; o >>= 1) { s += __shfl_down(s, o); ss += __shfl_down(ss, o); }
    __shared__ float ls[4], lss[4];
    int wid = threadIdx.x >> 6, lane = threadIdx.x & 63;
    if (lane == 0) { ls[wid] = s; lss[wid] = ss; }
    __syncthreads();
    if (threadIdx.x == 0) {
        part[blockIdx.x * 2]     = ls[0] + ls[1] + ls[2] + ls[3];
        part[blockIdx.x * 2 + 1] = lss[0] + lss[1] + lss[2] + lss[3];
    }
}

__global__ __launch_bounds__(256)
void finalize_stats(const float* __restrict__ part, float* __restrict__ stats) {
    float s = 0.f, ss = 0.f;
    for (int i = threadIdx.x; i < NB_RED; i += 256) { s += part[2 * i]; ss += part[2 * i + 1]; }
    #pragma unroll
    for (int o = 32; o > 0; o >>= 1) { s += __shfl_down(s, o); ss += __shfl_down(ss, o); }
    __shared__ float ls[4], lss[4];
    int wid = threadIdx.x >> 6, lane = threadIdx.x & 63;
    if (lane == 0) { ls[wid] = s; lss[wid] = ss; }
    __syncthreads();
    if (threadIdx.x == 0) {
        stats[0] = ls[0] + ls[1] + ls[2] + ls[3];
        stats[1] = lss[0] + lss[1] + lss[2] + lss[3];
    }
}

__global__ void norm_silu(float* __restrict__ y, const float* __restrict__ g,
                          const float* __restrict__ bb, const float* __restrict__ stats) {
    int i = blockIdx.x * 256 + threadIdx.x;
    if (i >= Cc * HW) return;
    const float invN = 1.f / (float)(Cc * HW);
    float mu  = stats[0] * invN;
    float var = stats[1] * invN - mu * mu;
    float inv = rsqrtf(var + 1e-5f);
    float z = (y[i] - mu) * inv * g[i] + bb[i];
    y[i] = z / (1.f + expf(-z));
}

// ---------------------------------------------------------------------------
// semilag fast path (pure fp32). Pole rows handled by sniper_rows.
// ---------------------------------------------------------------------------
__global__ __launch_bounds__(256)
void semilag(const float* __restrict__ vel, const float* __restrict__ hid,
             const float* __restrict__ latg, const float* __restrict__ lng,
             const float* __restrict__ dtp, float* __restrict__ out,
             u32* __restrict__ wl, u32* __restrict__ wlcnt)
{
    int idx = blockIdx.x * 256 + threadIdx.x;
    if (idx >= Cc * HW) return;
    int c = idx / HW;
    int m = idx - c * HW;

    const float PI2F = 6.28318530717958647692f;

    float uf = vel[idx];
    float vf = vel[Cc * HW + idx];
    float dtf = dtp[0];
    float phi = latg[m], lam = lng[m];
    float sphi = sinf(phi), cphi = cosf(phi);

    float lonp = -uf * dtf, latp = -vf * dtf;
    float slp = sinf(latp), clp = cosf(latp);
    float slo = sinf(lonp), clo = cosf(lonp);
    float sinlat = slp * cphi + clp * clo * sphi;
    float num = clp * slo;
    float den = clp * clo * cphi - slp * sphi;
    float r2 = num * num + den * den;

    float lon_w = lam + atan2f(num, den) + PI2F;
    lon_w = lon_w - floorf(lon_w / PI2F) * PI2F;
    float seam = fminf(lon_w, PI2F - lon_w);

    bool pole = (m < 2 * Ww) | (m >= HW - 2 * Ww);
    bool snipe = !pole & ((r2 < 1e-4f) | (fabsf(sinlat) > 1.f - 1e-5f) | (seam < 1e-3f));
    if (snipe) {
        u32 s = atomicAdd(wlcnt, 1u);
        if (s < WLCAP) wl[s] = (u32)idx;
    }

    float sl = fminf(fmaxf(sinlat, -1.f + 1e-7f), 1.f - 1e-7f);
    float lat_dep = asinf(sl);
    float gx = (lon_w / PI2F * 2.f - 1.f) * (480.f / 482.f);
    float gy = (lat_dep / 3.14159265358979323846f * 2.f - 1.f) * (240.f / 242.f);
    double ixd = (double)fminf(fmaxf((gx + 1.f) * 0.5f * 481.f, 0.f), 481.f);
    double iyd = (double)fminf(fmaxf((gy + 1.f) * 0.5f * 241.f, 0.f), 241.f);

    double x0d = floor(ixd), y0d = floor(iyd);
    float fx = (float)(ixd - x0d), fy = (float)(iyd - y0d);
    int x0 = (int)x0d, y0 = (int)y0d;

    const float a = -0.75f;
    float wx[4], wy[4];
    {
        float t = fx;
        float t1 = 1.f + t, t2 = 2.f - t, s1 = 1.f - t;
        wx[0] = ((a * t1 - 5.f * a) * t1 + 8.f * a) * t1 - 4.f * a;
        wx[1] = ((a + 2.f) * t - (a + 3.f)) * t * t + 1.f;
        wx[2] = ((a + 2.f) * s1 - (a + 3.f)) * s1 * s1 + 1.f;
        wx[3] = ((a * t2 - 5.f * a) * t2 + 8.f * a) * t2 - 4.f * a;
        t = fy;
        t1 = 1.f + t; t2 = 2.f - t; s1 = 1.f - t;
        wy[0] = ((a * t1 - 5.f * a) * t1 + 8.f * a) * t1 - 4.f * a;
        wy[1] = ((a + 2.f) * t - (a + 3.f)) * t * t + 1.f;
        wy[2] = ((a + 2.f) * s1 - (a + 3.f)) * s1 * s1 + 1.f;
        wy[3] = ((a * t2 - 5.f * a) * t2 + 8.f * a) * t2 - 4.f * a;
    }

    const float* plane = hid + (size_t)c * HW;
    float accv = 0.f;
    #pragma unroll
    for (int i = 0; i < 4; i++) {
        int yi = min(max(y0 + i - 1, 0), 241);
        float row = 0.f;
        #pragma unroll
        for (int j = 0; j < 4; j++) {
            int xj = min(max(x0 + j - 1, 0), 481);
            row = fmaf(wx[j], padfetch(plane, yi, xj), row);
        }
        accv = fmaf(wy[i], row, accv);
    }
    out[idx] = accv;
}

// ---------------------------------------------------------------------------
// sniper_rows: pole rows {0,1,238,239} — one block per spatial pixel.
// ---------------------------------------------------------------------------
__global__ __launch_bounds__(256)
void sniper_rows(const float* __restrict__ y1, const float* __restrict__ w2,
                 const float* __restrict__ b2, const float* __restrict__ hid,
                 const float* __restrict__ latg, const float* __restrict__ lng,
                 const float* __restrict__ dtp, float* __restrict__ out)
{
    __shared__ float xl[Kk];
    __shared__ double resd[256];

    const int tid = threadIdx.x;
    const int ri  = blockIdx.x / Ww;
    const int col = blockIdx.x - ri * Ww;
    const int r   = (ri < 2) ? ri : (236 + ri);   // 0,1,238,239
    const int m   = r * Ww + col;

    for (int k = tid; k < Kk; k += 256) {
        int ic = k / 9, t9 = k - ic * 9;
        xl[k] = y1[ic * HW + geo_sidx(r + t9 / 3 - 1, col + t9 % 3 - 1)];
    }
    __syncthreads();

    {
        const float* wrow = w2 + (size_t)tid * Kk;
        double a0 = 0.0, a1 = 0.0, a2 = 0.0, a3 = 0.0;
        #pragma unroll 4
        for (int k = 0; k < Kk; k += 4) {
            a0 = fma((double)wrow[k],     (double)xl[k],     a0);
            a1 = fma((double)wrow[k + 1], (double)xl[k + 1], a1);
            a2 = fma((double)wrow[k + 2], (double)xl[k + 2], a2);
            a3 = fma((double)wrow[k + 3], (double)xl[k + 3], a3);
        }
        resd[tid] = (a0 + a1) + (a2 + a3);
    }
    __syncthreads();

    if (tid < Cc) {
        double u = (double)b2[tid] + resd[tid];
        double v = (double)b2[Cc + tid] + resd[Cc + tid];
        double dt = (double)dtp[0];
        double phi = (double)latg[m];
        snipe_tail(u, v, dt, sin(phi), cos(phi), (double)lng[m],
                   hid + (size_t)tid * HW, &out[(size_t)tid * HW + m]);
    }
}

// ---------------------------------------------------------------------------
// sniper: per worklist entry (non-pole stragglers), one wave per entry.
// ---------------------------------------------------------------------------
__global__ __launch_bounds__(256)
void sniper(const u32* __restrict__ wl, const u32* __restrict__ wlcnt,
            const float* __restrict__ y1, const float* __restrict__ w2,
            const float* __restrict__ b2, const float* __restrict__ hid,
            const float* __restrict__ latg, const float* __restrict__ lng,
            const float* __restrict__ dtp, float* __restrict__ out)
{
    const int lane = threadIdx.x & 63;
    const int wavid = (blockIdx.x * 256 + threadIdx.x) >> 6;
    const int nwaves = gridDim.x * 4;
    int n = (int)*wlcnt; if (n > WLCAP) n = WLCAP;

    for (int e = wavid; e < n; e += nwaves) {
        u32 idx = wl[e];
        int c = idx / HW, m = idx - c * HW;
        int h = m / Ww, w = m - h * Ww;

        double su = 0.0, sv = 0.0;
        const float* wu = w2 + (size_t)c * Kk;
        const float* wv = w2 + (size_t)(Cc + c) * Kk;
        #pragma unroll
        for (int t9 = 0; t9 < 9; t9++) {
            int s = geo_sidx(h + t9 / 3 - 1, w + t9 % 3 - 1);
            #pragma unroll
            for (int q = 0; q < 2; q++) {
                int ic = q * 64 + lane;
                int k = ic * 9 + t9;
                double yv = (double)y1[ic * HW + s];
                su = fma((double)wu[k], yv, su);
                sv = fma((double)wv[k], yv, sv);
            }
        }
        #pragma unroll
        for (int o = 32; o > 0; o >>= 1) {
            su += __shfl_down(su, o);
            sv += __shfl_down(sv, o);
        }
        if (lane == 0) {
            double u = (double)b2[c] + su;
            double v = (double)b2[Cc + c] + sv;
            double dt = (double)dtp[0];
            double phi = (double)latg[m];
            snipe_tail(u, v, dt, sin(phi), cos(phi), (double)lng[m],
                       hid + (size_t)c * HW, &out[idx]);
        }
    }
}

// ---------------------------------------------------------------------------
extern "C" void kernel_launch(void* const* d_in, const int* in_sizes, int n_in,
                              void* d_out, int out_size, void* d_ws, size_t ws_size,
                              hipStream_t stream)
{
    const float* hidden = (const float*)d_in[0];
    const float* latg   = (const float*)d_in[1];
    const float* lng    = (const float*)d_in[2];
    const float* w1     = (const float*)d_in[3];
    const float* b1     = (const float*)d_in[4];
    const float* g      = (const float*)d_in[5];
    const float* lb     = (const float*)d_in[6];
    const float* w2     = (const float*)d_in[7];
    const float* b2     = (const float*)d_in[8];
    const float* dt     = (const float*)d_in[9];
    float* out = (float*)d_out;

    float* ws    = (float*)d_ws;
    float* stats = ws;
    float* part  = ws + 4;
    u32*   wlcnt = (u32*)(ws + 4 + 2 * NB_RED);
    u16*   wsp1  = (u16*)(ws + 4 + 2 * NB_RED + 4);
    u16*   wsp2  = wsp1 + (size_t)3 * Cc * Kk;
    float* y1    = (float*)(wsp2 + (size_t)3 * 2 * Cc * Kk);
    float* vel   = y1 + (size_t)Cc * HW;
    u32*   wl    = (u32*)(vel + (size_t)2 * Cc * HW);

    reorder_w<<<(3 * Cc * Kk + 255) / 256, 256, 0, stream>>>(w1, wsp1, Cc);
    reorder_w<<<(3 * 2 * Cc * Kk + 255) / 256, 256, 0, stream>>>(w2, wsp2, 2 * Cc);

    for (int b = 0; b < 2; b++) {
        const float* hb = hidden + (size_t)b * Cc * HW;
        const float* lab = latg + (size_t)b * HW;
        const float* lob = lng + (size_t)b * HW;
        float* ob = out + (size_t)b * Cc * HW;

        conv_mfma<128><<<HW / 128, 512, 0, stream>>>(hb, wsp1, b1, y1);
        reduce_stats<<<NB_RED, 256, 0, stream>>>(y1, part);
        finalize_stats<<<1, 256, 0, stream>>>(part, stats + 2 * b);
        norm_silu<<<(Cc * HW) / 256, 256, 0, stream>>>(y1, g, lb, stats + 2 * b);
        conv_mfma<256><<<HW / 128, 512, 0, stream>>>(y1, wsp2, b2, vel);
        hipMemsetAsync(wlcnt, 0, 4, stream);
        semilag<<<(Cc * HW) / 256, 256, 0, stream>>>(vel, hb, lab, lob, dt, ob, wl, wlcnt);
        sniper_rows<<<4 * Ww, 256, 0, stream>>>(y1, w2, b2, hb, lab, lob, dt, ob);
        sniper<<<2048, 256, 0, stream>>>(wl, wlcnt, y1, w2, b2, hb, lab, lob, dt, ob);
    }
}